// Round 13
// baseline (154.922 us; speedup 1.0000x reference)
//
#include <hip/hip_runtime.h>
#include <hip/hip_bf16.h>
#include <cstdint>
#include <cstddef>

#define DD 200
#define NN 20000
#define EE 320000
#define RRR 512
#define KP 256      // padded K stride (u16)
#define KREAL 224   // 7 * 32 covers K=200
#define MT 157      // node M tiles (157*128 = 20096)
#define NT 10       // node N tiles (1280 cols, 1200 real)
#define RMT 4
#define RNT 4
#define NBLK_NODE (MT * NT)
#define NBLK_GEMM (NBLK_NODE + RMT * RNT)
#define NBLK_SCAT ((EE + 255) / 256)
#define LOG2E 1.4426950408889634f

// XCD swizzle constants for the GEMM block range (m204 bijective form)
#define NXCD 8
#define SWZ_Q (NBLK_GEMM / NXCD)          // 198
#define SWZ_R (NBLK_GEMM % NXCD)          // 2

// kPrep block ranges
#define PB_NODE 10000                 // 20000*128 u32 / 256
#define PB_REL  (PB_NODE + 256)       // 512*128 u32 / 256
#define PB_HIST (PB_REL + 1250)
#define PB_W    (PB_HIST + 200)
#define PB_CQ   (PB_W + 1)
#define PB_PAD  (PB_CQ + 196)         // 1792 cols * 28 u32 = 50176 = 196*256

typedef __attribute__((ext_vector_type(8))) short bf16x8;
typedef __attribute__((ext_vector_type(4))) float f32x4;

__device__ __forceinline__ float bf2f_lo(unsigned int u) { return __uint_as_float(u << 16); }
__device__ __forceinline__ float bf2f_hi(unsigned int u) { return __uint_as_float(u & 0xffff0000u); }
__device__ __forceinline__ unsigned short f2bf(float f) {
  unsigned int x = __float_as_uint(f);
  return (unsigned short)((x + 0x7fffu + ((x >> 16) & 1u)) >> 16);   // RNE
}
__device__ __forceinline__ unsigned int f2bf2(float a, float b) {
  return (unsigned int)f2bf(a) | ((unsigned int)f2bf(b) << 16);
}
// paired-column layout: logical pair p (== channel j), bit b -> physical col
__device__ __forceinline__ int bcol(int p, int b) {
  return ((p >> 4) << 5) + (p & 15) + (b << 4);
}
__device__ __forceinline__ void gl_lds16(const unsigned short* g, unsigned short* l) {
  __builtin_amdgcn_global_load_lds(
      (const __attribute__((address_space(1))) void*)g,
      (__attribute__((address_space(3))) void*)l, 16, 0, 0);
}

// ---- kPrep: all independent prep in one launch ------------------------------
__global__ __launch_bounds__(256) void kPrep(const float* __restrict__ node, const float* __restrict__ rel,
                                             const int* __restrict__ dst,
                                             const float* __restrict__ wt, const float* __restrict__ wq,
                                             const float* __restrict__ lw, const float* __restrict__ elw,
                                             unsigned int* __restrict__ Au, unsigned int* __restrict__ Arelu,
                                             int* __restrict__ deg,
                                             unsigned short* __restrict__ Bt, unsigned short* __restrict__ BtRel,
                                             float* __restrict__ cq) {
  int b = blockIdx.x, t = threadIdx.x;
  if (b < PB_NODE) {                       // node -> packed bf16, flat full-width
    int idx = b * 256 + t;                 // u32 index into Au
    int n = idx >> 7, k = idx & 127;
    unsigned v = 0;
    if (k < 100) { float2 f = ((const float2*)(node + (size_t)n * DD))[k]; v = f2bf2(f.x, f.y); }
    Au[idx] = v;
  } else if (b < PB_REL) {                 // rel -> packed bf16, flat full-width
    int idx = (b - PB_NODE) * 256 + t;
    int r = idx >> 7, k = idx & 127;
    unsigned v = 0;
    if (k < 100) { float2 f = ((const float2*)(rel + (size_t)r * DD))[k]; v = f2bf2(f.x, f.y); }
    Arelu[idx] = v;
  } else if (b < PB_HIST) {                // degree histogram
    int e = (b - PB_REL) * 256 + t;
    if (e < EE) atomicAdd(&deg[dst[e]], 1);
  } else if (b < PB_W) {                   // weight row k -> B panels (paired-col layout)
    int k = b - PB_HIST, j = t;
    if (j >= DD) return;
    const float* w0 = wt + (size_t)k * DD;              // W_s row k
    const float* w1 = wt + (size_t)(2 * DD + k) * DD;   // W_d row k
    const float* w2 = wt + (size_t)(DD + k) * DD;       // W_r row k
    float s0 = 0.f, s1 = 0.f, s2 = 0.f;
    for (int i = 0; i < DD; ++i) {
      float q = wq[i * DD + j];
      s0 = fmaf(w0[i], q, s0);
      s1 = fmaf(w1[i], q, s1);
      s2 = fmaf(w2[i], q, s2);
    }
    Bt[bcol(j, 0) * KP + k]       = f2bf(w0[j]);
    Bt[bcol(j, 1) * KP + k]       = f2bf(s0 * LOG2E);
    Bt[bcol(200 + j, 0) * KP + k] = f2bf(w1[j]);
    Bt[bcol(200 + j, 1) * KP + k] = f2bf(s1 * LOG2E);
    Bt[bcol(400 + j, 0) * KP + k] = f2bf(lw[k * DD + j]);
    Bt[bcol(400 + j, 1) * KP + k] = f2bf(elw[k * DD + j]);
    BtRel[bcol(j, 0) * KP + k]    = f2bf(w2[j]);
    BtRel[bcol(j, 1) * KP + k]    = f2bf(s2 * LOG2E);
  } else if (b < PB_CQ) {                  // cq = colsum(w_quad) * LOG2E
    int j = t; if (j >= DD) return;
    float s = 0.f;
    for (int i = 0; i < DD; ++i) s += wq[i * DD + j];
    cq[j] = s * LOG2E;
  } else {                                 // zero K-pad of BtAll (cols 0..1791, k 200..255)
    int idx = (b - PB_CQ) * 256 + t;       // < 50176
    ((unsigned int*)Bt)[(idx / 28) * 128 + 100 + idx % 28] = 0;
  }
}

// ---- k_scan: single-block, single-pass exclusive scan (thread owns 5 int4) --
__global__ __launch_bounds__(1024) void k_scan(const int* __restrict__ deg, int* __restrict__ offs) {
  __shared__ int wsum[16];
  int tid = threadIdx.x, lane = tid & 63, wv = tid >> 6;
  const int4* deg4 = (const int4*)deg;
  int4* offs4 = (int4*)offs;
  int4 v[5]; int ps[5]; int tsum = 0;
#pragma unroll
  for (int c = 0; c < 5; ++c) {
    int idx = tid * 5 + c;
    v[c] = (idx < 5000) ? deg4[idx] : make_int4(0, 0, 0, 0);
    ps[c] = tsum;
    tsum += v[c].x + v[c].y + v[c].z + v[c].w;
  }
  int x = tsum;
#pragma unroll
  for (int off = 1; off < 64; off <<= 1) {
    int y = __shfl_up(x, off, 64);
    if (lane >= off) x += y;
  }
  if (lane == 63) wsum[wv] = x;
  __syncthreads();
  if (wv == 0) {
    int w = (lane < 16) ? wsum[lane] : 0;
#pragma unroll
    for (int off = 1; off < 16; off <<= 1) {
      int y = __shfl_up(w, off, 64);
      if (lane >= off) w += y;
    }
    if (lane < 16) wsum[lane] = w;
  }
  __syncthreads();
  int pre = ((wv > 0) ? wsum[wv - 1] : 0) + x - tsum;
#pragma unroll
  for (int c = 0; c < 5; ++c) {
    int idx = tid * 5 + c;
    if (idx < 5000) {
      int a = pre + ps[c];
      int bq = a + v[c].x, cc = bq + v[c].y, d = cc + v[c].z;
      offs4[idx] = make_int4(a, bq, cc, d);
    }
  }
  if (tid == 0) offs[NN] = wsum[15];
}

// ---- k_gs: fused GEMM (XCD-swizzled, paired u32 C-write) + edge scatter -----
__global__ __launch_bounds__(256) void k_gs(const unsigned short* __restrict__ A,
                                            const unsigned short* __restrict__ Bt,
                                            unsigned int* __restrict__ NT2u32,
                                            const unsigned short* __restrict__ Arel,
                                            const unsigned short* __restrict__ BtRel,
                                            unsigned int* __restrict__ RelPu32,
                                            const int* __restrict__ esrc, const int* __restrict__ edst,
                                            const int* __restrict__ etyp, const float* __restrict__ fre,
                                            const int* __restrict__ offs, int* __restrict__ cursor,
                                            int2* __restrict__ erec) {
  __shared__ unsigned short As[128 * 32];
  __shared__ unsigned short Bs[128 * 32];
  if (blockIdx.x >= NBLK_GEMM) {           // ---- scatter path (identity mapping) ----
    int e = (blockIdx.x - NBLK_GEMM) * 256 + threadIdx.x;
    if (e >= EE) return;
    int d = edst[e];
    int p = offs[d] + atomicAdd(&cursor[d], 1);
    erec[p] = make_int2(esrc[e] | (etyp[e] << 15), __float_as_int(fre[e]));
    return;
  }
  // ---- GEMM path: XCD-chunk swizzle (T1, m204 bijective) ----
  {
    int pb = blockIdx.x;
    int xcd = pb % NXCD, i = pb / NXCD;
    int wg = (xcd < SWZ_R ? xcd * (SWZ_Q + 1) : SWZ_R * (SWZ_Q + 1) + (xcd - SWZ_R) * SWZ_Q) + i;
    bool isrel = wg >= NBLK_NODE;
    int bid, ntn;
    const unsigned short *Ag, *Bg;
    if (!isrel) { bid = wg; ntn = NT; Ag = A; Bg = Bt; }
    else        { bid = wg - NBLK_NODE; ntn = RNT; Ag = Arel; Bg = BtRel; }
    int mt = bid / ntn, nt = bid % ntn;
    int t = threadIdx.x, lane = t & 63, wv = t >> 6;
    int lr = lane & 15, k8 = lane >> 4;
    int wm = (wv >> 1) * 64, wn = (wv & 1) * 64;
    int sr = wv * 16 + (lane >> 2);
    int sc = lane & 3;
    f32x4 acc[4][4] = {};
    Ag += (size_t)(mt * 128) * KP;
    Bg += (size_t)(nt * 128) * KP;
    for (int kk = 0; kk < KREAL; kk += 32) {
#pragma unroll
      for (int i2 = 0; i2 < 2; ++i2) {
        int row = i2 * 64 + sr;
        int gcol = kk + ((sc ^ (row & 3)) << 3);
        gl_lds16(Ag + (size_t)row * KP + gcol, As + i2 * 2048 + wv * 512);
        gl_lds16(Bg + (size_t)row * KP + gcol, Bs + i2 * 2048 + wv * 512);
      }
      __syncthreads();
      bf16x8 af[4], bfr[4];
#pragma unroll
      for (int mi = 0; mi < 4; ++mi) {
        int row = wm + mi * 16 + lr;
        af[mi] = *(const bf16x8*)(As + row * 32 + ((k8 ^ (row & 3)) << 3));
        int col = wn + mi * 16 + lr;
        bfr[mi] = *(const bf16x8*)(Bs + col * 32 + ((k8 ^ (col & 3)) << 3));
      }
#pragma unroll
      for (int mi = 0; mi < 4; ++mi)
#pragma unroll
        for (int ni = 0; ni < 4; ++ni)
          acc[mi][ni] = __builtin_amdgcn_mfma_f32_16x16x32_bf16(af[mi], bfr[ni], acc[mi][ni], 0, 0, 0);
      __syncthreads();
    }
    // ---- epilogue: paired u32 stores, full-line coalesced ----
    int rb = k8 * 4;
    int pb16 = (nt * 128 + wn) >> 5;       // 32-col group base
#pragma unroll
    for (int mi = 0; mi < 4; ++mi)
#pragma unroll
      for (int np = 0; np < 2; ++np) {
        int p = (pb16 + np) * 16 + lr;     // pair index == logical channel slot
        if (!isrel) {
          if (p < 600) {
            int g = p / 200, w = p - g * 200;
            unsigned int* dstp = NT2u32 + (size_t)g * NN * 200 + w;
#pragma unroll
            for (int r = 0; r < 4; ++r) {
              int row = mt * 128 + wm + mi * 16 + rb + r;
              if (row < NN)
                dstp[(size_t)row * 200] = f2bf2(acc[mi][2 * np][r], acc[mi][2 * np + 1][r]);
            }
          }
        } else {
          if (p < 200) {
#pragma unroll
            for (int r = 0; r < 4; ++r) {
              int row = mt * 128 + wm + mi * 16 + rb + r;
              RelPu32[(size_t)row * 200 + p] = f2bf2(acc[mi][2 * np][r], acc[mi][2 * np + 1][r]);
            }
          }
        }
      }
  }
}

// ---- k_agg body: one (node, channel) per thread -----------------------------
__device__ __forceinline__ void agg_body(int n, int j,
                                         const unsigned int* __restrict__ GSu,
                                         const unsigned int* __restrict__ GDu,
                                         const unsigned int* __restrict__ GLu,
                                         const unsigned int* __restrict__ Relu,
                                         const float* __restrict__ cq,
                                         const float* __restrict__ norm,
                                         const int* __restrict__ offs,
                                         const int2* __restrict__ erec,
                                         float* __restrict__ out) {
  int e0 = offs[n], e1 = offs[n + 1];
  unsigned dp = GDu[(size_t)n * DD + j];
  float xq = bf2f_hi(dp);
  float cqj = cq[j];
  float s = 0.f, num = 0.f;
#define DO_EDGE(SP, RP, FI)                                                   \
  {                                                                           \
    float F = __int_as_float(FI);                                             \
    float t0 = bf2f_lo(SP) + bf2f_lo(RP);                                     \
    float a0 = bf2f_hi(SP) + bf2f_hi(RP) + fmaf(F, cqj, xq);                  \
    a0 = fmaxf(a0, 0.01f * a0);                                               \
    float ev = exp2f(a0);                                                     \
    s += ev; num = fmaf(ev, t0, num);                                         \
  }
  int i = e0;
  for (; i + 4 <= e1; i += 4) {
    int2 r0 = erec[i], r1 = erec[i + 1], r2 = erec[i + 2], r3 = erec[i + 3];
    unsigned g0 = GSu[(unsigned)(r0.x & 0x7fff) * 200u + j];
    unsigned g1 = GSu[(unsigned)(r1.x & 0x7fff) * 200u + j];
    unsigned g2 = GSu[(unsigned)(r2.x & 0x7fff) * 200u + j];
    unsigned g3 = GSu[(unsigned)(r3.x & 0x7fff) * 200u + j];
    unsigned R0 = Relu[((unsigned)r0.x >> 15) * 200u + j];
    unsigned R1 = Relu[((unsigned)r1.x >> 15) * 200u + j];
    unsigned R2 = Relu[((unsigned)r2.x >> 15) * 200u + j];
    unsigned R3 = Relu[((unsigned)r3.x >> 15) * 200u + j];
    DO_EDGE(g0, R0, r0.y)
    DO_EDGE(g1, R1, r1.y)
    DO_EDGE(g2, R2, r2.y)
    DO_EDGE(g3, R3, r3.y)
  }
  for (; i < e1; ++i) {
    int2 r = erec[i];
    unsigned g = GSu[(unsigned)(r.x & 0x7fff) * 200u + j];
    unsigned R = Relu[((unsigned)r.x >> 15) * 200u + j];
    DO_EDGE(g, R, r.y)
  }
#undef DO_EDGE
  unsigned lp = GLu[(size_t)n * DD + j];
  float o;
  if (e1 > e0) o = (num / s + bf2f_lo(dp)) * norm[n] + bf2f_lo(lp);
  else         o = bf2f_hi(lp);
  out[(size_t)n * DD + j] = fmaxf(o, 0.f);
}

// ---- k_agg: channel-split with XCD affinity. block b: channel group g=b&7
//      (25 u32 channels) for 10 nodes (b>>3)*10 .. +9. Under round-robin
//      dispatch all blocks of group g land on XCD g, whose GS column-slice
//      (20000 x 25 u32 = 2 MB) stays L2-resident -> gather re-reads hit L2. --
__global__ __launch_bounds__(256) void k_agg(const unsigned int* __restrict__ GSu,
                                             const unsigned int* __restrict__ GDu,
                                             const unsigned int* __restrict__ GLu,
                                             const unsigned int* __restrict__ Relu,
                                             const float* __restrict__ cq,
                                             const float* __restrict__ norm,
                                             const int* __restrict__ offs,
                                             const int2* __restrict__ erec,
                                             float* __restrict__ out) {
  int t = threadIdx.x;
  if (t >= 250) return;
  int g = blockIdx.x & 7;
  int seg = t / 25;
  int n = (blockIdx.x >> 3) * 10 + seg;
  int j = g * 25 + t - seg * 25;
  agg_body(n, j, GSu, GDu, GLu, Relu, cq, norm, offs, erec, out);
}

extern "C" void kernel_launch(void* const* d_in, const int* in_sizes, int n_in,
                              void* d_out, int out_size, void* d_ws, size_t ws_size,
                              hipStream_t stream) {
  const float* node = (const float*)d_in[0];
  const float* rel  = (const float*)d_in[1];
  const float* norm = (const float*)d_in[2];
  const float* fre  = (const float*)d_in[3];
  const float* wt   = (const float*)d_in[4];
  const float* wq   = (const float*)d_in[5];
  const float* lw   = (const float*)d_in[6];
  const float* elw  = (const float*)d_in[7];
  const int* esrc = (const int*)d_in[8];
  const int* edst = (const int*)d_in[9];
  const int* etyp = (const int*)d_in[10];
  float* out = (float*)d_out;

  char* p = (char*)d_ws;
  auto carve = [&](size_t bytes) -> char* {
    char* r = p; p += (bytes + 255) & ~(size_t)255; return r;
  };
  unsigned short* A     = (unsigned short*)carve((size_t)(MT * 128) * KP * 2);
  unsigned short* Arel  = (unsigned short*)carve((size_t)RRR * KP * 2);
  unsigned short* BtAll = (unsigned short*)carve((size_t)(1280 + 512) * KP * 2);
  unsigned short* NT2   = (unsigned short*)carve((size_t)3 * NN * 400 * 2);
  unsigned short* RelP  = (unsigned short*)carve((size_t)RRR * 400 * 2);
  float* cq   = (float*)carve((size_t)DD * 4);
  int* degcur = (int*)carve((size_t)2 * NN * 4);     // deg | cursor
  int* offs   = (int*)carve((size_t)(NN + 1) * 4);
  int2* erec  = (int2*)carve((size_t)EE * 8);

  unsigned short* Bt    = BtAll;
  unsigned short* BtRel = BtAll + (size_t)1280 * KP;
  int* deg    = degcur;
  int* cursor = degcur + NN;

  const unsigned int* GSu = (const unsigned int*)NT2;
  const unsigned int* GDu = GSu + (size_t)NN * DD;
  const unsigned int* GLu = GSu + (size_t)2 * NN * DD;

  hipMemsetAsync(degcur, 0, (size_t)2 * NN * 4, stream);
  kPrep<<<PB_PAD, 256, 0, stream>>>(node, rel, edst, wt, wq, lw, elw,
                                    (unsigned int*)A, (unsigned int*)Arel, deg, Bt, BtRel, cq);
  k_scan<<<1, 1024, 0, stream>>>(deg, offs);
  k_gs<<<NBLK_GEMM + NBLK_SCAT, 256, 0, stream>>>(A, Bt, (unsigned int*)NT2, Arel, BtRel,
                                                  (unsigned int*)RelP,
                                                  esrc, edst, etyp, fre, offs, cursor, erec);
  k_agg<<<(NN / 10) * 8, 256, 0, stream>>>(GSu, GDu, GLu, (const unsigned int*)RelP, cq,
                                           norm, offs, erec, out);
}

// Round 14
// 125.673 us; speedup vs baseline: 1.2327x; 1.2327x over previous
//
#include <hip/hip_runtime.h>
#include <hip/hip_bf16.h>
#include <cstdint>
#include <cstddef>

#define DD 200
#define NN 20000
#define EE 320000
#define RRR 512
#define KP 256      // padded K stride (u16)
#define KREAL 224   // 7 * 32 covers K=200
#define MT 157      // node M tiles (157*128 = 20096)
#define NT 10       // node N tiles (1280 cols, 1200 real)
#define RMT 4
#define RNT 4
#define NBLK_NODE (MT * NT)
#define NBLK_GEMM (NBLK_NODE + RMT * RNT)
#define NBLK_SCAT ((EE + 255) / 256)
#define LOG2E 1.4426950408889634f

// XCD swizzle constants for the GEMM block range (m204 bijective form)
#define NXCD 8
#define SWZ_Q (NBLK_GEMM / NXCD)          // 198
#define SWZ_R (NBLK_GEMM % NXCD)          // 2

// kPrep block ranges
#define PB_NODE 10000                 // 20000*128 u32 / 256
#define PB_REL  (PB_NODE + 256)       // 512*128 u32 / 256
#define PB_HIST (PB_REL + 1250)
#define PB_W    (PB_HIST + 200)
#define PB_CQ   (PB_W + 1)
#define PB_PAD  (PB_CQ + 196)         // 1792 cols * 28 u32 = 50176 = 196*256

typedef __attribute__((ext_vector_type(8))) short bf16x8;
typedef __attribute__((ext_vector_type(4))) float f32x4;

__device__ __forceinline__ float bf2f_lo(unsigned int u) { return __uint_as_float(u << 16); }
__device__ __forceinline__ float bf2f_hi(unsigned int u) { return __uint_as_float(u & 0xffff0000u); }
__device__ __forceinline__ unsigned short f2bf(float f) {
  unsigned int x = __float_as_uint(f);
  return (unsigned short)((x + 0x7fffu + ((x >> 16) & 1u)) >> 16);   // RNE
}
__device__ __forceinline__ unsigned int f2bf2(float a, float b) {
  return (unsigned int)f2bf(a) | ((unsigned int)f2bf(b) << 16);
}
// paired-column layout: logical pair p (== channel j), bit b -> physical col
__device__ __forceinline__ int bcol(int p, int b) {
  return ((p >> 4) << 5) + (p & 15) + (b << 4);
}
__device__ __forceinline__ void gl_lds16(const unsigned short* g, unsigned short* l) {
  __builtin_amdgcn_global_load_lds(
      (const __attribute__((address_space(1))) void*)g,
      (__attribute__((address_space(3))) void*)l, 16, 0, 0);
}

// ---- kPrep: all independent prep in one launch ------------------------------
__global__ __launch_bounds__(256) void kPrep(const float* __restrict__ node, const float* __restrict__ rel,
                                             const int* __restrict__ dst,
                                             const float* __restrict__ wt, const float* __restrict__ wq,
                                             const float* __restrict__ lw, const float* __restrict__ elw,
                                             unsigned int* __restrict__ Au, unsigned int* __restrict__ Arelu,
                                             int* __restrict__ deg,
                                             unsigned short* __restrict__ Bt, unsigned short* __restrict__ BtRel,
                                             float* __restrict__ cq) {
  int b = blockIdx.x, t = threadIdx.x;
  if (b < PB_NODE) {                       // node -> packed bf16, flat full-width
    int idx = b * 256 + t;                 // u32 index into Au
    int n = idx >> 7, k = idx & 127;
    unsigned v = 0;
    if (k < 100) { float2 f = ((const float2*)(node + (size_t)n * DD))[k]; v = f2bf2(f.x, f.y); }
    Au[idx] = v;
  } else if (b < PB_REL) {                 // rel -> packed bf16, flat full-width
    int idx = (b - PB_NODE) * 256 + t;
    int r = idx >> 7, k = idx & 127;
    unsigned v = 0;
    if (k < 100) { float2 f = ((const float2*)(rel + (size_t)r * DD))[k]; v = f2bf2(f.x, f.y); }
    Arelu[idx] = v;
  } else if (b < PB_HIST) {                // degree histogram
    int e = (b - PB_REL) * 256 + t;
    if (e < EE) atomicAdd(&deg[dst[e]], 1);
  } else if (b < PB_W) {                   // weight row k -> B panels (paired-col layout)
    int k = b - PB_HIST, j = t;
    if (j >= DD) return;
    const float* w0 = wt + (size_t)k * DD;              // W_s row k
    const float* w1 = wt + (size_t)(2 * DD + k) * DD;   // W_d row k
    const float* w2 = wt + (size_t)(DD + k) * DD;       // W_r row k
    float s0 = 0.f, s1 = 0.f, s2 = 0.f;
    for (int i = 0; i < DD; ++i) {
      float q = wq[i * DD + j];
      s0 = fmaf(w0[i], q, s0);
      s1 = fmaf(w1[i], q, s1);
      s2 = fmaf(w2[i], q, s2);
    }
    Bt[bcol(j, 0) * KP + k]       = f2bf(w0[j]);
    Bt[bcol(j, 1) * KP + k]       = f2bf(s0 * LOG2E);
    Bt[bcol(200 + j, 0) * KP + k] = f2bf(w1[j]);
    Bt[bcol(200 + j, 1) * KP + k] = f2bf(s1 * LOG2E);
    Bt[bcol(400 + j, 0) * KP + k] = f2bf(lw[k * DD + j]);
    Bt[bcol(400 + j, 1) * KP + k] = f2bf(elw[k * DD + j]);
    BtRel[bcol(j, 0) * KP + k]    = f2bf(w2[j]);
    BtRel[bcol(j, 1) * KP + k]    = f2bf(s2 * LOG2E);
  } else if (b < PB_CQ) {                  // cq = colsum(w_quad) * LOG2E
    int j = t; if (j >= DD) return;
    float s = 0.f;
    for (int i = 0; i < DD; ++i) s += wq[i * DD + j];
    cq[j] = s * LOG2E;
  } else {                                 // zero K-pad of BtAll (cols 0..1791, k 200..255)
    int idx = (b - PB_CQ) * 256 + t;       // < 50176
    ((unsigned int*)Bt)[(idx / 28) * 128 + 100 + idx % 28] = 0;
  }
}

// ---- k_scan: single-block, single-pass exclusive scan (thread owns 5 int4) --
__global__ __launch_bounds__(1024) void k_scan(const int* __restrict__ deg, int* __restrict__ offs) {
  __shared__ int wsum[16];
  int tid = threadIdx.x, lane = tid & 63, wv = tid >> 6;
  const int4* deg4 = (const int4*)deg;
  int4* offs4 = (int4*)offs;
  int4 v[5]; int ps[5]; int tsum = 0;
#pragma unroll
  for (int c = 0; c < 5; ++c) {
    int idx = tid * 5 + c;
    v[c] = (idx < 5000) ? deg4[idx] : make_int4(0, 0, 0, 0);
    ps[c] = tsum;
    tsum += v[c].x + v[c].y + v[c].z + v[c].w;
  }
  int x = tsum;
#pragma unroll
  for (int off = 1; off < 64; off <<= 1) {
    int y = __shfl_up(x, off, 64);
    if (lane >= off) x += y;
  }
  if (lane == 63) wsum[wv] = x;
  __syncthreads();
  if (wv == 0) {
    int w = (lane < 16) ? wsum[lane] : 0;
#pragma unroll
    for (int off = 1; off < 16; off <<= 1) {
      int y = __shfl_up(w, off, 64);
      if (lane >= off) w += y;
    }
    if (lane < 16) wsum[lane] = w;
  }
  __syncthreads();
  int pre = ((wv > 0) ? wsum[wv - 1] : 0) + x - tsum;
#pragma unroll
  for (int c = 0; c < 5; ++c) {
    int idx = tid * 5 + c;
    if (idx < 5000) {
      int a = pre + ps[c];
      int bq = a + v[c].x, cc = bq + v[c].y, d = cc + v[c].z;
      offs4[idx] = make_int4(a, bq, cc, d);
    }
  }
  if (tid == 0) offs[NN] = wsum[15];
}

// ---- k_gs: fused GEMM (XCD-swizzled, paired u32 C-write) + edge scatter -----
__global__ __launch_bounds__(256) void k_gs(const unsigned short* __restrict__ A,
                                            const unsigned short* __restrict__ Bt,
                                            unsigned int* __restrict__ NT2u32,
                                            const unsigned short* __restrict__ Arel,
                                            const unsigned short* __restrict__ BtRel,
                                            unsigned int* __restrict__ RelPu32,
                                            const int* __restrict__ esrc, const int* __restrict__ edst,
                                            const int* __restrict__ etyp, const float* __restrict__ fre,
                                            const int* __restrict__ offs, int* __restrict__ cursor,
                                            int2* __restrict__ erec) {
  __shared__ unsigned short As[128 * 32];
  __shared__ unsigned short Bs[128 * 32];
  if (blockIdx.x >= NBLK_GEMM) {           // ---- scatter path (identity mapping) ----
    int e = (blockIdx.x - NBLK_GEMM) * 256 + threadIdx.x;
    if (e >= EE) return;
    int d = edst[e];
    int p = offs[d] + atomicAdd(&cursor[d], 1);
    erec[p] = make_int2(esrc[e] | (etyp[e] << 15), __float_as_int(fre[e]));
    return;
  }
  // ---- GEMM path: XCD-chunk swizzle (T1, m204 bijective) ----
  {
    int pb = blockIdx.x;
    int xcd = pb % NXCD, i = pb / NXCD;
    int wg = (xcd < SWZ_R ? xcd * (SWZ_Q + 1) : SWZ_R * (SWZ_Q + 1) + (xcd - SWZ_R) * SWZ_Q) + i;
    bool isrel = wg >= NBLK_NODE;
    int bid, ntn;
    const unsigned short *Ag, *Bg;
    if (!isrel) { bid = wg; ntn = NT; Ag = A; Bg = Bt; }
    else        { bid = wg - NBLK_NODE; ntn = RNT; Ag = Arel; Bg = BtRel; }
    int mt = bid / ntn, nt = bid % ntn;
    int t = threadIdx.x, lane = t & 63, wv = t >> 6;
    int lr = lane & 15, k8 = lane >> 4;
    int wm = (wv >> 1) * 64, wn = (wv & 1) * 64;
    int sr = wv * 16 + (lane >> 2);
    int sc = lane & 3;
    f32x4 acc[4][4] = {};
    Ag += (size_t)(mt * 128) * KP;
    Bg += (size_t)(nt * 128) * KP;
    for (int kk = 0; kk < KREAL; kk += 32) {
#pragma unroll
      for (int i2 = 0; i2 < 2; ++i2) {
        int row = i2 * 64 + sr;
        int gcol = kk + ((sc ^ (row & 3)) << 3);
        gl_lds16(Ag + (size_t)row * KP + gcol, As + i2 * 2048 + wv * 512);
        gl_lds16(Bg + (size_t)row * KP + gcol, Bs + i2 * 2048 + wv * 512);
      }
      __syncthreads();
      bf16x8 af[4], bfr[4];
#pragma unroll
      for (int mi = 0; mi < 4; ++mi) {
        int row = wm + mi * 16 + lr;
        af[mi] = *(const bf16x8*)(As + row * 32 + ((k8 ^ (row & 3)) << 3));
        int col = wn + mi * 16 + lr;
        bfr[mi] = *(const bf16x8*)(Bs + col * 32 + ((k8 ^ (col & 3)) << 3));
      }
#pragma unroll
      for (int mi = 0; mi < 4; ++mi)
#pragma unroll
        for (int ni = 0; ni < 4; ++ni)
          acc[mi][ni] = __builtin_amdgcn_mfma_f32_16x16x32_bf16(af[mi], bfr[ni], acc[mi][ni], 0, 0, 0);
      __syncthreads();
    }
    // ---- epilogue: paired u32 stores, full-line coalesced ----
    int rb = k8 * 4;
    int pb16 = (nt * 128 + wn) >> 5;       // 32-col group base
#pragma unroll
    for (int mi = 0; mi < 4; ++mi)
#pragma unroll
      for (int np = 0; np < 2; ++np) {
        int p = (pb16 + np) * 16 + lr;     // pair index == logical channel slot
        if (!isrel) {
          if (p < 600) {
            int g = p / 200, w = p - g * 200;
            unsigned int* dstp = NT2u32 + (size_t)g * NN * 200 + w;
#pragma unroll
            for (int r = 0; r < 4; ++r) {
              int row = mt * 128 + wm + mi * 16 + rb + r;
              if (row < NN)
                dstp[(size_t)row * 200] = f2bf2(acc[mi][2 * np][r], acc[mi][2 * np + 1][r]);
            }
          }
        } else {
          if (p < 200) {
#pragma unroll
            for (int r = 0; r < 4; ++r) {
              int row = mt * 128 + wm + mi * 16 + rb + r;
              RelPu32[(size_t)row * 200 + p] = f2bf2(acc[mi][2 * np][r], acc[mi][2 * np + 1][r]);
            }
          }
        }
      }
  }
}

// ---- k_agg body: one (node, channel) per thread. UNI=true: n is wave-uniform
//      -> erec/fre indices forced to SGPR via readfirstlane so edge records go
//      through s_load (constant cache), freeing VMEM slots for the gathers. ---
template <bool UNI>
__device__ __forceinline__ void agg_body(int n, int j,
                                         const unsigned int* __restrict__ GSu,
                                         const unsigned int* __restrict__ GDu,
                                         const unsigned int* __restrict__ GLu,
                                         const unsigned int* __restrict__ Relu,
                                         const float* __restrict__ cq,
                                         const float* __restrict__ norm,
                                         const int* __restrict__ offs,
                                         const int2* __restrict__ erec,
                                         float* __restrict__ out) {
  int e0 = offs[n], e1 = offs[n + 1];
  if (UNI) {
    e0 = __builtin_amdgcn_readfirstlane(e0);
    e1 = __builtin_amdgcn_readfirstlane(e1);
  }
  unsigned dp = GDu[(size_t)n * DD + j];
  float xq = bf2f_hi(dp);
  float cqj = cq[j];
  float s = 0.f, num = 0.f;
#define DO_EDGE(SP, RP, FI)                                                   \
  {                                                                           \
    float F = __int_as_float(FI);                                             \
    float t0 = bf2f_lo(SP) + bf2f_lo(RP);                                     \
    float a0 = bf2f_hi(SP) + bf2f_hi(RP) + fmaf(F, cqj, xq);                  \
    a0 = fmaxf(a0, 0.01f * a0);                                               \
    float ev = exp2f(a0);                                                     \
    s += ev; num = fmaf(ev, t0, num);                                         \
  }
  int i = e0;
  for (; i + 4 <= e1; i += 4) {
    int2 r0 = erec[i], r1 = erec[i + 1], r2 = erec[i + 2], r3 = erec[i + 3];
    unsigned g0 = GSu[(unsigned)(r0.x & 0x7fff) * 200u + j];
    unsigned g1 = GSu[(unsigned)(r1.x & 0x7fff) * 200u + j];
    unsigned g2 = GSu[(unsigned)(r2.x & 0x7fff) * 200u + j];
    unsigned g3 = GSu[(unsigned)(r3.x & 0x7fff) * 200u + j];
    unsigned R0 = Relu[((unsigned)r0.x >> 15) * 200u + j];
    unsigned R1 = Relu[((unsigned)r1.x >> 15) * 200u + j];
    unsigned R2 = Relu[((unsigned)r2.x >> 15) * 200u + j];
    unsigned R3 = Relu[((unsigned)r3.x >> 15) * 200u + j];
    DO_EDGE(g0, R0, r0.y)
    DO_EDGE(g1, R1, r1.y)
    DO_EDGE(g2, R2, r2.y)
    DO_EDGE(g3, R3, r3.y)
  }
  for (; i < e1; ++i) {
    int2 r = erec[i];
    unsigned g = GSu[(unsigned)(r.x & 0x7fff) * 200u + j];
    unsigned R = Relu[((unsigned)r.x >> 15) * 200u + j];
    DO_EDGE(g, R, r.y)
  }
#undef DO_EDGE
  unsigned lp = GLu[(size_t)n * DD + j];
  float o;
  if (e1 > e0) o = (num / s + bf2f_lo(dp)) * norm[n] + bf2f_lo(lp);
  else         o = bf2f_hi(lp);
  out[(size_t)n * DD + j] = fmaxf(o, 0.f);
}

// ---- k_agg: waves 0-2 -> ch 0..191 of node blockIdx (uniform n, scalar erec);
//      wave 3 -> ch 192..199 of 8 nodes (blocks < NN/8), else retires. --------
__global__ __launch_bounds__(256) void k_agg(const unsigned int* __restrict__ GSu,
                                             const unsigned int* __restrict__ GDu,
                                             const unsigned int* __restrict__ GLu,
                                             const unsigned int* __restrict__ Relu,
                                             const float* __restrict__ cq,
                                             const float* __restrict__ norm,
                                             const int* __restrict__ offs,
                                             const int2* __restrict__ erec,
                                             float* __restrict__ out) {
  int t = threadIdx.x;
  if (t < 192) {
    agg_body<true>(blockIdx.x, t, GSu, GDu, GLu, Relu, cq, norm, offs, erec, out);
  } else {
    if (blockIdx.x >= NN / 8) return;      // wave retires, frees issue slot
    int lane = t - 192;                    // 0..63
    int n = blockIdx.x * 8 + (lane >> 3);
    int j = 192 + (lane & 7);
    agg_body<false>(n, j, GSu, GDu, GLu, Relu, cq, norm, offs, erec, out);
  }
}

extern "C" void kernel_launch(void* const* d_in, const int* in_sizes, int n_in,
                              void* d_out, int out_size, void* d_ws, size_t ws_size,
                              hipStream_t stream) {
  const float* node = (const float*)d_in[0];
  const float* rel  = (const float*)d_in[1];
  const float* norm = (const float*)d_in[2];
  const float* fre  = (const float*)d_in[3];
  const float* wt   = (const float*)d_in[4];
  const float* wq   = (const float*)d_in[5];
  const float* lw   = (const float*)d_in[6];
  const float* elw  = (const float*)d_in[7];
  const int* esrc = (const int*)d_in[8];
  const int* edst = (const int*)d_in[9];
  const int* etyp = (const int*)d_in[10];
  float* out = (float*)d_out;

  char* p = (char*)d_ws;
  auto carve = [&](size_t bytes) -> char* {
    char* r = p; p += (bytes + 255) & ~(size_t)255; return r;
  };
  unsigned short* A     = (unsigned short*)carve((size_t)(MT * 128) * KP * 2);
  unsigned short* Arel  = (unsigned short*)carve((size_t)RRR * KP * 2);
  unsigned short* BtAll = (unsigned short*)carve((size_t)(1280 + 512) * KP * 2);
  unsigned short* NT2   = (unsigned short*)carve((size_t)3 * NN * 400 * 2);
  unsigned short* RelP  = (unsigned short*)carve((size_t)RRR * 400 * 2);
  float* cq   = (float*)carve((size_t)DD * 4);
  int* degcur = (int*)carve((size_t)2 * NN * 4);     // deg | cursor
  int* offs   = (int*)carve((size_t)(NN + 1) * 4);
  int2* erec  = (int2*)carve((size_t)EE * 8);

  unsigned short* Bt    = BtAll;
  unsigned short* BtRel = BtAll + (size_t)1280 * KP;
  int* deg    = degcur;
  int* cursor = degcur + NN;

  const unsigned int* GSu = (const unsigned int*)NT2;
  const unsigned int* GDu = GSu + (size_t)NN * DD;
  const unsigned int* GLu = GSu + (size_t)2 * NN * DD;

  hipMemsetAsync(degcur, 0, (size_t)2 * NN * 4, stream);
  kPrep<<<PB_PAD, 256, 0, stream>>>(node, rel, edst, wt, wq, lw, elw,
                                    (unsigned int*)A, (unsigned int*)Arel, deg, Bt, BtRel, cq);
  k_scan<<<1, 1024, 0, stream>>>(deg, offs);
  k_gs<<<NBLK_GEMM + NBLK_SCAT, 256, 0, stream>>>(A, Bt, (unsigned int*)NT2, Arel, BtRel,
                                                  (unsigned int*)RelP,
                                                  esrc, edst, etyp, fre, offs, cursor, erec);
  k_agg<<<NN, 256, 0, stream>>>(GSu, GDu, GLu, (const unsigned int*)RelP, cq,
                                norm, offs, erec, out);
}